// Round 6
// baseline (135.886 us; speedup 1.0000x reference)
//
#include <hip/hip_runtime.h>
#include <hip/hip_bf16.h>
#include <math.h>

#define LOG2PI_F 1.8378770664093453f

typedef __bf16 bf16_t;
typedef bf16_t bf16x8 __attribute__((ext_vector_type(8)));
typedef bf16_t bf16x4 __attribute__((ext_vector_type(4)));
typedef float f32x4 __attribute__((ext_vector_type(4)));

#define M_DIM 16384
#define K_DIM 2048
#define N_DIM 2048
#define BM 256
#define BN 256
#define BK 64
#define NB_N (N_DIM / BN) /* 8 */
#define NB_M (M_DIM / BM) /* 64 */

// async global->LDS, 16B per lane. LDS dest is wave-uniform base + lane*16.
__device__ __forceinline__ void gload16(const void* g, void* l) {
    __builtin_amdgcn_global_load_lds(
        (__attribute__((address_space(1))) void*)g,
        (__attribute__((address_space(3))) void*)l, 16, 0, 0);
}

// ---------------------------------------------------------------------------
// Build Lt[j][i] = L[i][j] in bf16 + partial sums of strict-lower Woff^2.
// ---------------------------------------------------------------------------
__global__ __launch_bounds__(256) void build_Lt(const float* __restrict__ Woff,
                                                const float* __restrict__ Wld,
                                                bf16_t* __restrict__ Lt,
                                                float* __restrict__ misc_arr) {
    __shared__ float tile[64][65];
    __shared__ float red[4];
    const int jt = blockIdx.x * 64;
    const int it = blockIdx.y * 64;
    const int tid = threadIdx.x;
    float ss = 0.f;

    if (it + 63 >= jt) {
        for (int e = tid; e < 4096; e += 256) {
            int r = e >> 6, c = e & 63;
            tile[r][c] = Woff[(size_t)(it + r) * K_DIM + (jt + c)];
        }
    }
    __syncthreads();

    for (int e = tid; e < 4096; e += 256) {
        int jr = e >> 6, ic = e & 63;
        int i = it + ic, j = jt + jr;
        float v = 0.f;
        if (i > j) {
            v = tile[ic][jr];
            ss += v * v;
        } else if (i == j) {
            v = expf(Wld[i]);
        }
        Lt[(size_t)j * K_DIM + i] = (bf16_t)v;
    }

    #pragma unroll
    for (int off = 32; off; off >>= 1) ss += __shfl_down(ss, off);
    if ((tid & 63) == 0) red[tid >> 6] = ss;
    __syncthreads();
    if (tid == 0)
        misc_arr[blockIdx.y * 32 + blockIdx.x] = red[0] + red[1] + red[2] + red[3];
}

// ---------------------------------------------------------------------------
// Cast x -> bf16 and fuse pred_mean GEMV u[b] = dot(x[b], W_mean).
// ---------------------------------------------------------------------------
__global__ __launch_bounds__(256) void prep_x(const float* __restrict__ X,
                                              const float* __restrict__ Wm,
                                              bf16_t* __restrict__ Xb,
                                              float* __restrict__ U) {
    const int b = blockIdx.x;
    const int tid = threadIdx.x;
    const float* xr = X + (size_t)b * K_DIM;
    bf16_t* xo = Xb + (size_t)b * K_DIM;
    __shared__ float red[4];
    float dot = 0.f;
    #pragma unroll
    for (int h = 0; h < 2; ++h) {
        int base = h * 1024 + tid * 4;
        float4 v = *(const float4*)(xr + base);
        float4 w = *(const float4*)(Wm + base);
        dot += v.x * w.x + v.y * w.y + v.z * w.z + v.w * w.w;
        bf16x4 p = {(bf16_t)v.x, (bf16_t)v.y, (bf16_t)v.z, (bf16_t)v.w};
        *(bf16x4*)(xo + base) = p;
    }
    #pragma unroll
    for (int off = 32; off; off >>= 1) dot += __shfl_down(dot, off);
    if ((tid & 63) == 0) red[tid >> 6] = dot;
    __syncthreads();
    if (tid == 0) U[b] = red[0] + red[1] + red[2] + red[3];
}

// ---------------------------------------------------------------------------
// quad_gemm 256x256, BK=64, 8-phase-per-2-halves schedule (T3+T4+T5).
// 8 waves (2M x 4N); per wave 128x64 out = acc[8][4].
// LDS: [2 buf][2 ks-half] x 256rows x 32k for A and B  (128 KB).
// Per K-tile: 4 phases (mh,ks) = (0,0),(1,0),(0,1),(1,1); each phase:
//   ds_read sub-tile frags | stage one half-tile | barrier |
//   setprio(1) 16 MFMA setprio(0) | barrier.
// Half-tile stream (group t): p0: A.K1(t+1)  p1: B.K1(t+1)
//                             p2: B.K0(t+2)  p3: A.K0(t+2)
// Every staged slot is >=1 barrier past its last reader. Group-end wait:
// vmcnt(4) keeps tile t+2's two K0 halves in flight (counted, not drain).
// ---------------------------------------------------------------------------
__device__ __forceinline__ bf16x8 ldsfragK(const bf16_t* half_, int row, int g) {
    int off = row * 64 + (((g ^ row) & 3) << 4);  // 64B rows, chunk^=(row&3)
    return *(const bf16x8*)((const char*)half_ + off);
}

__global__ __launch_bounds__(512, 2) void quad_gemm(const bf16_t* __restrict__ Xb,
                                                    const bf16_t* __restrict__ Lt,
                                                    float* __restrict__ qpart) {
    __shared__ bf16_t As[2][2][256 * 32];   // [buf][ks][row*32+k]  64 KB
    __shared__ bf16_t Bs[2][2][256 * 32];   // 64 KB

    const int mb = blockIdx.x, nb = blockIdx.y;
    const int tid = threadIdx.x;
    const int lane = tid & 63;
    const int wid = tid >> 6;               // 0..7
    const int wr = wid >> 2, wc = wid & 3;  // 2M x 4N wave grid
    const int g = lane >> 4, r16 = lane & 15;
    const int brow = mb * BM, bcol = nb * BN;
    const int NT = (K_DIM - bcol) >> 6;     // 32 - 4*nb, in [4,32]

    // staging source (pre-swizzled chunk, involution with read XOR):
    // per gload16: 16 rows x 64B; lane -> row_off = lane>>2, chunk = lane&3.
    const int srow = lane >> 2;                  // 0..15
    const int kch = (lane & 3) ^ (srow & 3);     // swizzled k-chunk (8 bf16)
    // row j=0: wid*16+srow (rows 0..127); j=1: +128.
    const bf16_t* pA0 = Xb + (size_t)(brow + wid * 16 + srow) * K_DIM + bcol + kch * 8;
    const bf16_t* pA1 = pA0 + (size_t)128 * K_DIM;
    const bf16_t* pB0 = Lt + (size_t)(bcol + wid * 16 + srow) * K_DIM + bcol + kch * 8;
    const bf16_t* pB1 = pB0 + (size_t)128 * K_DIM;

#define STG_A(T, KS) {                                                   \
        char* d_ = (char*)As[(T) & 1][KS] + wid * 1024;                  \
        gload16(pA0 + (size_t)(T) * 64 + (KS) * 32, d_);                 \
        gload16(pA1 + (size_t)(T) * 64 + (KS) * 32, d_ + 8192); }
#define STG_B(T, KS) {                                                   \
        char* d_ = (char*)Bs[(T) & 1][KS] + wid * 1024;                  \
        gload16(pB0 + (size_t)(T) * 64 + (KS) * 32, d_);                 \
        gload16(pB1 + (size_t)(T) * 64 + (KS) * 32, d_ + 8192); }
#define BAR() asm volatile("s_barrier" ::: "memory")

    f32x4 acc[8][4];
    const f32x4 zero = {0.f, 0.f, 0.f, 0.f};
    #pragma unroll
    for (int m = 0; m < 8; ++m)
        #pragma unroll
        for (int n = 0; n < 4; ++n) acc[m][n] = zero;

    // prologue: tile0 full + tile1 K0 halves; vmcnt(4) -> tile0 landed.
    STG_A(0, 0) STG_B(0, 0) STG_A(0, 1) STG_B(0, 1)
    STG_B(1, 0) STG_A(1, 0)
    asm volatile("s_waitcnt vmcnt(4)" ::: "memory");
    BAR();

    for (int t = 0; t < NT; ++t) {
        const bf16_t* A0 = As[t & 1][0];
        const bf16_t* A1 = As[t & 1][1];
        const bf16_t* B0 = Bs[t & 1][0];
        const bf16_t* B1 = Bs[t & 1][1];
        const bool s1 = (t + 1 < NT), s2 = (t + 2 < NT);
        bf16x8 a[4], b[4];

        // ---- phase 0: (mh0, ks0) -- reads A.K0, B.K0
        #pragma unroll
        for (int n = 0; n < 4; ++n) b[n] = ldsfragK(B0, wc * 64 + n * 16 + r16, g);
        #pragma unroll
        for (int m = 0; m < 4; ++m) a[m] = ldsfragK(A0, wr * 128 + m * 16 + r16, g);
        if (s1) STG_A(t + 1, 1)
        BAR();
        __builtin_amdgcn_s_setprio(1);
        #pragma unroll
        for (int m = 0; m < 4; ++m)
            #pragma unroll
            for (int n = 0; n < 4; ++n)
                acc[m][n] = __builtin_amdgcn_mfma_f32_16x16x32_bf16(a[m], b[n], acc[m][n], 0, 0, 0);
        __builtin_amdgcn_s_setprio(0);
        BAR();

        // ---- phase 1: (mh1, ks0) -- reads A.K0 only (b cached)
        #pragma unroll
        for (int m = 0; m < 4; ++m) a[m] = ldsfragK(A0, wr * 128 + 64 + m * 16 + r16, g);
        if (s1) STG_B(t + 1, 1)
        BAR();
        __builtin_amdgcn_s_setprio(1);
        #pragma unroll
        for (int m = 0; m < 4; ++m)
            #pragma unroll
            for (int n = 0; n < 4; ++n)
                acc[4 + m][n] = __builtin_amdgcn_mfma_f32_16x16x32_bf16(a[m], b[n], acc[4 + m][n], 0, 0, 0);
        __builtin_amdgcn_s_setprio(0);
        BAR();

        // ---- phase 2: (mh0, ks1) -- reads A.K1, B.K1; B.K0 slot now dead
        #pragma unroll
        for (int n = 0; n < 4; ++n) b[n] = ldsfragK(B1, wc * 64 + n * 16 + r16, g);
        #pragma unroll
        for (int m = 0; m < 4; ++m) a[m] = ldsfragK(A1, wr * 128 + m * 16 + r16, g);
        if (s2) STG_B(t + 2, 0)
        BAR();
        __builtin_amdgcn_s_setprio(1);
        #pragma unroll
        for (int m = 0; m < 4; ++m)
            #pragma unroll
            for (int n = 0; n < 4; ++n)
                acc[m][n] = __builtin_amdgcn_mfma_f32_16x16x32_bf16(a[m], b[n], acc[m][n], 0, 0, 0);
        __builtin_amdgcn_s_setprio(0);
        BAR();

        // ---- phase 3: (mh1, ks1) -- reads A.K1 only; A.K0 slot dead
        #pragma unroll
        for (int m = 0; m < 4; ++m) a[m] = ldsfragK(A1, wr * 128 + 64 + m * 16 + r16, g);
        if (s2) STG_A(t + 2, 0)
        BAR();
        __builtin_amdgcn_s_setprio(1);
        #pragma unroll
        for (int m = 0; m < 4; ++m)
            #pragma unroll
            for (int n = 0; n < 4; ++n)
                acc[4 + m][n] = __builtin_amdgcn_mfma_f32_16x16x32_bf16(a[m], b[n], acc[4 + m][n], 0, 0, 0);
        __builtin_amdgcn_s_setprio(0);

        // ---- group end: counted wait (tile t+1 fully lands; t+2's K0 stays
        // in flight). Only the tail ever drains.
        if (s2)
            asm volatile("s_waitcnt vmcnt(4)" ::: "memory");
        else if (s1)
            asm volatile("s_waitcnt vmcnt(0)" ::: "memory");
        BAR();
    }

    // epilogue: per-row sum of squares over this block's 256 cols.
    // acc m = mh*4+mi -> row wr*128 + mh*64 + mi*16 + g*4 + r; col wc*64+n*16+r16
    float* qbuf = (float*)&As[0][0][0];  // 4 KB scratch; staging fully drained
    __syncthreads();
    #pragma unroll
    for (int m = 0; m < 8; ++m) {
        #pragma unroll
        for (int r = 0; r < 4; ++r) {
            float s = 0.f;
            #pragma unroll
            for (int n = 0; n < 4; ++n) {
                float t = acc[m][n][r];
                s += t * t;
            }
            #pragma unroll
            for (int off = 1; off < 16; off <<= 1) s += __shfl_xor(s, off);
            int row = wr * 128 + (m >> 2) * 64 + (m & 3) * 16 + g * 4 + r;
            if (r16 == 0) qbuf[wc * 256 + row] = s;
        }
    }
    __syncthreads();
    if (tid < BM)
        qpart[(size_t)(brow + tid) * NB_N + nb] =
            qbuf[tid] + qbuf[256 + tid] + qbuf[512 + tid] + qbuf[768 + tid];
#undef STG_A
#undef STG_B
#undef BAR
}

// ---------------------------------------------------------------------------
// row_part: 32-block partial reduction of the per-row weighted ELBO terms.
// ---------------------------------------------------------------------------
__global__ __launch_bounds__(256) void row_part(const float* __restrict__ Y,
                                                const float* __restrict__ Cnt,
                                                const float* __restrict__ nld_p,
                                                const float* __restrict__ U,
                                                const float* __restrict__ qpart,
                                                double* __restrict__ dpart) {
    const int tid = threadIdx.x;
    const float nld = nld_p[0];
    const float inv_sig = expf(-nld);
    const float nprec = inv_sig * inv_sig;
    double s1 = 0.0, s2 = 0.0;
    const int base = blockIdx.x * 512;
    #pragma unroll
    for (int j = 0; j < 2; ++j) {
        int b = base + j * 256 + tid;
        float c = Cnt[b];
        const float4* qp = (const float4*)(qpart + (size_t)b * NB_N);
        float4 q0 = qp[0], q1 = qp[1];
        float q = q0.x + q0.y + q0.z + q0.w + q1.x + q1.y + q1.z + q1.w;
        float d = (Y[b] - U[b]) * inv_sig;
        float pl = -0.5f * d * d - nld - 0.5f * LOG2PI_F;
        float tt = 0.5f * q * c * c * nprec;
        s1 += (double)c;
        s2 += (double)((pl - tt) * c);
    }
    __shared__ double red[2][4];
    #pragma unroll
    for (int off = 32; off; off >>= 1) {
        s1 += __shfl_down(s1, off);
        s2 += __shfl_down(s2, off);
    }
    if ((tid & 63) == 0) { red[0][tid >> 6] = s1; red[1][tid >> 6] = s2; }
    __syncthreads();
    if (tid == 0) {
        dpart[blockIdx.x * 2 + 0] = red[0][0] + red[0][1] + red[0][2] + red[0][3];
        dpart[blockIdx.x * 2 + 1] = red[1][0] + red[1][1] + red[1][2] + red[1][3];
    }
}

// ---------------------------------------------------------------------------
// finalize2: combine partials + KL/wishart scalar terms. One block.
// ---------------------------------------------------------------------------
__global__ __launch_bounds__(256) void finalize2(const float* __restrict__ nld_p,
                                                 const float* __restrict__ Wm,
                                                 const float* __restrict__ Wld,
                                                 const double* __restrict__ dpart,
                                                 const float* __restrict__ misc_arr,
                                                 float* __restrict__ out) {
    const int tid = threadIdx.x;
    const float nld = nld_p[0];
    const float inv_sig = expf(-nld);
    const float nprec = inv_sig * inv_sig;

    double s1 = 0.0, s2 = 0.0;
    if (tid < 32) { s1 = dpart[tid * 2]; s2 = dpart[tid * 2 + 1]; }

    double wm2 = 0.0, tcd = 0.0, wls = 0.0, offs = 0.0;
    for (int i = tid; i < K_DIM; i += 256) {
        float w = Wm[i];
        wm2 += (double)w * (double)w;
        float ld = Wld[i];
        tcd += exp(2.0 * (double)ld);
        wls += (double)ld;
    }
    for (int i = tid; i < 1024; i += 256) offs += (double)misc_arr[i];

    __shared__ double red[6][4];
    double vals[6] = {s1, s2, wm2, tcd, wls, offs};
    #pragma unroll
    for (int s = 0; s < 6; ++s) {
        double v = vals[s];
        #pragma unroll
        for (int off = 32; off; off >>= 1) v += __shfl_down(v, off);
        if ((tid & 63) == 0) red[s][tid >> 6] = v;
    }
    __syncthreads();
    if (tid == 0) {
        double S1 = red[0][0] + red[0][1] + red[0][2] + red[0][3];
        double S2 = red[1][0] + red[1][1] + red[1][2] + red[1][3];
        double MSE = red[2][0] + red[2][1] + red[2][2] + red[2][3];
        double TCD = red[3][0] + red[3][1] + red[3][2] + red[3][3];
        double WLS = red[4][0] + red[4][1] + red[4][2] + red[4][3];
        double OFFS = red[5][0] + red[5][1] + red[5][2] + red[5][3];

        double trace_cov = OFFS + TCD;                   // sum(L*L)
        double kl = 0.5 * (MSE + trace_cov - 2.0 * WLS); // prior_scale=1
        double wish = 1.5 * (-2.0 * (double)nld) - 0.005 * (double)nprec;
        double elbo = S2 / S1 + 1e-4 * (wish - kl);
        out[0] = (float)(-elbo);
    }
}

// ---------------------------------------------------------------------------
extern "C" void kernel_launch(void* const* d_in, const int* in_sizes, int n_in,
                              void* d_out, int out_size, void* d_ws, size_t ws_size,
                              hipStream_t stream) {
    const float* x    = (const float*)d_in[0];
    const float* y    = (const float*)d_in[1];
    const float* cnt  = (const float*)d_in[2];
    // d_in[3] = noise_mean (unused by the reference math)
    const float* nld  = (const float*)d_in[4];
    const float* Wm   = (const float*)d_in[5];
    const float* Wld  = (const float*)d_in[6];
    const float* Woff = (const float*)d_in[7];

    char* ws = (char*)d_ws;
    bf16_t* Xb     = (bf16_t*)(ws);                 // [0, 67108864)
    bf16_t* Lt     = (bf16_t*)(ws + 67108864);      // [67108864, 75497472)
    float*  U      = (float*)(ws + 75497472);       // 16384*4
    float*  qpart  = (float*)(ws + 75563008);       // 16384*8*4 = 512 KB
    float*  misc   = (float*)(ws + 76611584);       // 1024*4
    // dpart (512 B) aliases Lt's base: Lt is consumed only by quad_gemm,
    // which completes before row_part writes here; build_Lt rewrites Lt
    // at the start of every launch, so replays stay deterministic.
    double* dpart  = (double*)(ws + 67108864);

    build_Lt<<<dim3(32, 32), 256, 0, stream>>>(Woff, Wld, Lt, misc);
    prep_x<<<dim3(M_DIM), 256, 0, stream>>>(x, Wm, Xb, U);
    quad_gemm<<<dim3(NB_M, NB_N), 512, 0, stream>>>(Xb, Lt, qpart);
    row_part<<<dim3(32), 256, 0, stream>>>(y, cnt, nld, U, qpart, dpart);
    finalize2<<<1, 256, 0, stream>>>(nld, Wm, Wld, dpart, misc, (float*)d_out);
}

// Round 7
// 133.912 us; speedup vs baseline: 1.0147x; 1.0147x over previous
//
#include <hip/hip_runtime.h>
#include <hip/hip_bf16.h>
#include <math.h>

#define LOG2PI_F 1.8378770664093453f

typedef __bf16 bf16_t;
typedef bf16_t bf16x8 __attribute__((ext_vector_type(8)));
typedef bf16_t bf16x4 __attribute__((ext_vector_type(4)));
typedef float f32x4 __attribute__((ext_vector_type(4)));

#define M_DIM 16384
#define K_DIM 2048
#define N_DIM 2048
#define BM 256
#define BN 256
#define BK 64
#define NB_N (N_DIM / BN) /* 8 */
#define NB_M (M_DIM / BM) /* 64 */

// async global->LDS, 16B per lane. LDS dest is wave-uniform base + lane*16.
__device__ __forceinline__ void gload16(const void* g, void* l) {
    __builtin_amdgcn_global_load_lds(
        (__attribute__((address_space(1))) void*)g,
        (__attribute__((address_space(3))) void*)l, 16, 0, 0);
}

// ---------------------------------------------------------------------------
// Build Lt[j][i] = L[i][j] in bf16 + partial sums of strict-lower Woff^2.
// ---------------------------------------------------------------------------
__global__ __launch_bounds__(256) void build_Lt(const float* __restrict__ Woff,
                                                const float* __restrict__ Wld,
                                                bf16_t* __restrict__ Lt,
                                                float* __restrict__ misc_arr) {
    __shared__ float tile[64][65];
    __shared__ float red[4];
    const int jt = blockIdx.x * 64;
    const int it = blockIdx.y * 64;
    const int tid = threadIdx.x;
    float ss = 0.f;

    if (it + 63 >= jt) {
        for (int e = tid; e < 4096; e += 256) {
            int r = e >> 6, c = e & 63;
            tile[r][c] = Woff[(size_t)(it + r) * K_DIM + (jt + c)];
        }
    }
    __syncthreads();

    for (int e = tid; e < 4096; e += 256) {
        int jr = e >> 6, ic = e & 63;
        int i = it + ic, j = jt + jr;
        float v = 0.f;
        if (i > j) {
            v = tile[ic][jr];
            ss += v * v;
        } else if (i == j) {
            v = expf(Wld[i]);
        }
        Lt[(size_t)j * K_DIM + i] = (bf16_t)v;
    }

    #pragma unroll
    for (int off = 32; off; off >>= 1) ss += __shfl_down(ss, off);
    if ((tid & 63) == 0) red[tid >> 6] = ss;
    __syncthreads();
    if (tid == 0)
        misc_arr[blockIdx.y * 32 + blockIdx.x] = red[0] + red[1] + red[2] + red[3];
}

// ---------------------------------------------------------------------------
// Cast x -> bf16 and fuse pred_mean GEMV u[b] = dot(x[b], W_mean).
// ---------------------------------------------------------------------------
__global__ __launch_bounds__(256) void prep_x(const float* __restrict__ X,
                                              const float* __restrict__ Wm,
                                              bf16_t* __restrict__ Xb,
                                              float* __restrict__ U) {
    const int b = blockIdx.x;
    const int tid = threadIdx.x;
    const float* xr = X + (size_t)b * K_DIM;
    bf16_t* xo = Xb + (size_t)b * K_DIM;
    __shared__ float red[4];
    float dot = 0.f;
    #pragma unroll
    for (int h = 0; h < 2; ++h) {
        int base = h * 1024 + tid * 4;
        float4 v = *(const float4*)(xr + base);
        float4 w = *(const float4*)(Wm + base);
        dot += v.x * w.x + v.y * w.y + v.z * w.z + v.w * w.w;
        bf16x4 p = {(bf16_t)v.x, (bf16_t)v.y, (bf16_t)v.z, (bf16_t)v.w};
        *(bf16x4*)(xo + base) = p;
    }
    #pragma unroll
    for (int off = 32; off; off >>= 1) dot += __shfl_down(dot, off);
    if ((tid & 63) == 0) red[tid >> 6] = dot;
    __syncthreads();
    if (tid == 0) U[b] = red[0] + red[1] + red[2] + red[3];
}

// ---------------------------------------------------------------------------
// quad_gemm 256x256, BK=64, 2-buf LDS, 8 waves (2M x 4N), R5 schedule
// (one barrier + one vmcnt per K-tile), load-balanced nb pairing:
// physical block (mb, j) runs logical tiles (mb, j) then (mb, 7-j);
// NT sums to 36 for every j => 256 equal blocks, 1 per CU, no tail.
// LDS layout: [row][64k] 128-B rows, read XOR (row&7)<<4 (conflict-free,
// R5-measured 0), source pre-swizzled involutively.
// ---------------------------------------------------------------------------
__device__ __forceinline__ bf16x8 ldsfrag(const bf16_t* base, int row, int ks, int g) {
    int byteoff = ((row * BK + ks * 32 + g * 8) * 2) ^ ((row & 7) << 4);
    return *(const bf16x8*)((const char*)base + byteoff);
}

__global__ __launch_bounds__(512, 2) void quad_gemm(const bf16_t* __restrict__ Xb,
                                                    const bf16_t* __restrict__ Lt,
                                                    float* __restrict__ qpart) {
    __shared__ bf16_t As[2][BM * BK];   // 2 x 32 KB
    __shared__ bf16_t Bs[2][BN * BK];   // 2 x 32 KB  (128 KB total)

    const int mb = blockIdx.x;
    const int jp = blockIdx.y;              // 0..3
    const int tid = threadIdx.x;
    const int lane = tid & 63;
    const int wid = tid >> 6;               // 0..7
    const int wr = wid >> 2, wc = wid & 3;  // 2M x 4N wave grid
    const int g = lane >> 4, r16 = lane & 15;
    const int brow = mb * BM;

    // staging source lane geometry (pre-swizzled chunk; involution w/ read XOR)
    const int srow = lane >> 3;             // row-within-8 == (ldsrow & 7)
    const int scol = (lane & 7) ^ srow;     // swizzled source chunk

    const bf16_t* pA[4];
    const bf16_t* pB[4];

#define STAGE(BUF)                                                          \
    { _Pragma("unroll") for (int j = 0; j < 4; ++j)                         \
          gload16(pA[j], (char*)As[BUF] + (wid * 4 + j) * 1024);            \
      _Pragma("unroll") for (int j = 0; j < 4; ++j)                         \
          gload16(pB[j], (char*)Bs[BUF] + (wid * 4 + j) * 1024);            \
      _Pragma("unroll") for (int j = 0; j < 4; ++j) { pA[j] += BK; pB[j] += BK; } }

    auto gemm_one = [&](int nb) {
        const int bcol = nb * BN;
        const int NT = (K_DIM - bcol) >> 6;   // in [4,32]

        #pragma unroll
        for (int j = 0; j < 4; ++j) {
            pA[j] = Xb + (size_t)(brow + wid * 32 + j * 8 + srow) * K_DIM + bcol + scol * 8;
            pB[j] = Lt + (size_t)(bcol + wid * 32 + j * 8 + srow) * K_DIM + bcol + scol * 8;
        }

        f32x4 acc[8][4];
        const f32x4 zero = {0.f, 0.f, 0.f, 0.f};
        #pragma unroll
        for (int m = 0; m < 8; ++m)
            #pragma unroll
            for (int n = 0; n < 4; ++n) acc[m][n] = zero;

        // prologue: tile 0 -> buf 0
        STAGE(0)
        asm volatile("s_waitcnt vmcnt(0)" ::: "memory");
        asm volatile("s_barrier" ::: "memory");

        for (int i = 0; i < NT; ++i) {
            const bf16_t* Ab = As[i & 1];
            const bf16_t* Bb = Bs[i & 1];
            const bool stg = (i + 1 < NT);
            if (stg) STAGE((i + 1) & 1)

            // ks-major quadrants: live frags <= b[4] + a (keeps VGPR low)
            #pragma unroll
            for (int ks = 0; ks < 2; ++ks) {
                bf16x8 b[4];
                #pragma unroll
                for (int n = 0; n < 4; ++n)
                    b[n] = ldsfrag(Bb, wc * 64 + n * 16 + r16, ks, g);
                __builtin_amdgcn_s_setprio(1);
                #pragma unroll
                for (int m = 0; m < 8; ++m) {
                    bf16x8 a = ldsfrag(Ab, wr * 128 + m * 16 + r16, ks, g);
                    #pragma unroll
                    for (int n = 0; n < 4; ++n)
                        acc[m][n] = __builtin_amdgcn_mfma_f32_16x16x32_bf16(
                            a, b[n], acc[m][n], 0, 0, 0);
                }
                __builtin_amdgcn_s_setprio(0);
            }

            if (stg)
                asm volatile("s_waitcnt vmcnt(0)" ::: "memory");  // tile i+1 landed
            asm volatile("s_barrier" ::: "memory");
        }

        // epilogue: per-row sum of squares over this block's 256 cols.
        // C/D: col = wc*64 + n*16 + r16, row = wr*128 + m*16 + g*4 + r
        float* qbuf = (float*)&As[0][0];  // 4 KB scratch (staging drained)
        __syncthreads();
        #pragma unroll
        for (int m = 0; m < 8; ++m) {
            #pragma unroll
            for (int r = 0; r < 4; ++r) {
                float s = 0.f;
                #pragma unroll
                for (int n = 0; n < 4; ++n) {
                    float t = acc[m][n][r];
                    s += t * t;
                }
                #pragma unroll
                for (int off = 1; off < 16; off <<= 1) s += __shfl_xor(s, off);
                if (r16 == 0) qbuf[wc * 256 + wr * 128 + m * 16 + g * 4 + r] = s;
            }
        }
        __syncthreads();
        if (tid < BM)
            qpart[(size_t)(brow + tid) * NB_N + nb] =
                qbuf[tid] + qbuf[256 + tid] + qbuf[512 + tid] + qbuf[768 + tid];
        __syncthreads();  // qbuf reads done before next gemm restages As[0]
    };

    gemm_one(jp);        // heavy: NT = 32 - 4*jp  (20..32)
    gemm_one(7 - jp);    // light: NT = 4 + 4*jp   (4..16); sum = 36 always
#undef STAGE
}

// ---------------------------------------------------------------------------
// row_part: 32-block partial reduction of the per-row weighted ELBO terms.
// ---------------------------------------------------------------------------
__global__ __launch_bounds__(256) void row_part(const float* __restrict__ Y,
                                                const float* __restrict__ Cnt,
                                                const float* __restrict__ nld_p,
                                                const float* __restrict__ U,
                                                const float* __restrict__ qpart,
                                                double* __restrict__ dpart) {
    const int tid = threadIdx.x;
    const float nld = nld_p[0];
    const float inv_sig = expf(-nld);
    const float nprec = inv_sig * inv_sig;
    double s1 = 0.0, s2 = 0.0;
    const int base = blockIdx.x * 512;
    #pragma unroll
    for (int j = 0; j < 2; ++j) {
        int b = base + j * 256 + tid;
        float c = Cnt[b];
        const float4* qp = (const float4*)(qpart + (size_t)b * NB_N);
        float4 q0 = qp[0], q1 = qp[1];
        float q = q0.x + q0.y + q0.z + q0.w + q1.x + q1.y + q1.z + q1.w;
        float d = (Y[b] - U[b]) * inv_sig;
        float pl = -0.5f * d * d - nld - 0.5f * LOG2PI_F;
        float tt = 0.5f * q * c * c * nprec;
        s1 += (double)c;
        s2 += (double)((pl - tt) * c);
    }
    __shared__ double red[2][4];
    #pragma unroll
    for (int off = 32; off; off >>= 1) {
        s1 += __shfl_down(s1, off);
        s2 += __shfl_down(s2, off);
    }
    if ((tid & 63) == 0) { red[0][tid >> 6] = s1; red[1][tid >> 6] = s2; }
    __syncthreads();
    if (tid == 0) {
        dpart[blockIdx.x * 2 + 0] = red[0][0] + red[0][1] + red[0][2] + red[0][3];
        dpart[blockIdx.x * 2 + 1] = red[1][0] + red[1][1] + red[1][2] + red[1][3];
    }
}

// ---------------------------------------------------------------------------
// finalize2: combine partials + KL/wishart scalar terms. One block.
// ---------------------------------------------------------------------------
__global__ __launch_bounds__(256) void finalize2(const float* __restrict__ nld_p,
                                                 const float* __restrict__ Wm,
                                                 const float* __restrict__ Wld,
                                                 const double* __restrict__ dpart,
                                                 const float* __restrict__ misc_arr,
                                                 float* __restrict__ out) {
    const int tid = threadIdx.x;
    const float nld = nld_p[0];
    const float inv_sig = expf(-nld);
    const float nprec = inv_sig * inv_sig;

    double s1 = 0.0, s2 = 0.0;
    if (tid < 32) { s1 = dpart[tid * 2]; s2 = dpart[tid * 2 + 1]; }

    double wm2 = 0.0, tcd = 0.0, wls = 0.0, offs = 0.0;
    for (int i = tid; i < K_DIM; i += 256) {
        float w = Wm[i];
        wm2 += (double)w * (double)w;
        float ld = Wld[i];
        tcd += exp(2.0 * (double)ld);
        wls += (double)ld;
    }
    for (int i = tid; i < 1024; i += 256) offs += (double)misc_arr[i];

    __shared__ double red[6][4];
    double vals[6] = {s1, s2, wm2, tcd, wls, offs};
    #pragma unroll
    for (int s = 0; s < 6; ++s) {
        double v = vals[s];
        #pragma unroll
        for (int off = 32; off; off >>= 1) v += __shfl_down(v, off);
        if ((tid & 63) == 0) red[s][tid >> 6] = v;
    }
    __syncthreads();
    if (tid == 0) {
        double S1 = red[0][0] + red[0][1] + red[0][2] + red[0][3];
        double S2 = red[1][0] + red[1][1] + red[1][2] + red[1][3];
        double MSE = red[2][0] + red[2][1] + red[2][2] + red[2][3];
        double TCD = red[3][0] + red[3][1] + red[3][2] + red[3][3];
        double WLS = red[4][0] + red[4][1] + red[4][2] + red[4][3];
        double OFFS = red[5][0] + red[5][1] + red[5][2] + red[5][3];

        double trace_cov = OFFS + TCD;                   // sum(L*L)
        double kl = 0.5 * (MSE + trace_cov - 2.0 * WLS); // prior_scale=1
        double wish = 1.5 * (-2.0 * (double)nld) - 0.005 * (double)nprec;
        double elbo = S2 / S1 + 1e-4 * (wish - kl);
        out[0] = (float)(-elbo);
    }
}

// ---------------------------------------------------------------------------
extern "C" void kernel_launch(void* const* d_in, const int* in_sizes, int n_in,
                              void* d_out, int out_size, void* d_ws, size_t ws_size,
                              hipStream_t stream) {
    const float* x    = (const float*)d_in[0];
    const float* y    = (const float*)d_in[1];
    const float* cnt  = (const float*)d_in[2];
    // d_in[3] = noise_mean (unused by the reference math)
    const float* nld  = (const float*)d_in[4];
    const float* Wm   = (const float*)d_in[5];
    const float* Wld  = (const float*)d_in[6];
    const float* Woff = (const float*)d_in[7];

    char* ws = (char*)d_ws;
    bf16_t* Xb     = (bf16_t*)(ws);                 // [0, 67108864)
    bf16_t* Lt     = (bf16_t*)(ws + 67108864);      // [67108864, 75497472)
    float*  U      = (float*)(ws + 75497472);       // 16384*4
    float*  qpart  = (float*)(ws + 75563008);       // 16384*8*4 = 512 KB
    float*  misc   = (float*)(ws + 76611584);       // 1024*4
    // dpart (512 B) aliases Lt's base: Lt is consumed only by quad_gemm,
    // which completes before row_part writes here; build_Lt rewrites Lt
    // at the start of every launch, so replays stay deterministic.
    double* dpart  = (double*)(ws + 67108864);

    build_Lt<<<dim3(32, 32), 256, 0, stream>>>(Woff, Wld, Lt, misc);
    prep_x<<<dim3(M_DIM), 256, 0, stream>>>(x, Wm, Xb, U);
    quad_gemm<<<dim3(NB_M, 4), 512, 0, stream>>>(Xb, Lt, qpart);
    row_part<<<dim3(32), 256, 0, stream>>>(y, cnt, nld, U, qpart, dpart);
    finalize2<<<1, 256, 0, stream>>>(nld, Wm, Wld, dpart, misc, (float*)d_out);
}

// Round 8
// 128.204 us; speedup vs baseline: 1.0599x; 1.0445x over previous
//
#include <hip/hip_runtime.h>
#include <hip/hip_bf16.h>
#include <math.h>

#define LOG2PI_F 1.8378770664093453f

typedef __bf16 bf16_t;
typedef bf16_t bf16x8 __attribute__((ext_vector_type(8)));
typedef bf16_t bf16x4 __attribute__((ext_vector_type(4)));
typedef float f32x4 __attribute__((ext_vector_type(4)));

#define M_DIM 16384
#define K_DIM 2048
#define N_DIM 2048
#define BM 256
#define BN 256
#define BK 64
#define NB_N (N_DIM / BN) /* 8 */
#define NB_M (M_DIM / BM) /* 64 */

// async global->LDS, 16B per lane. LDS dest is wave-uniform base + lane*16.
__device__ __forceinline__ void gload16(const void* g, void* l) {
    __builtin_amdgcn_global_load_lds(
        (__attribute__((address_space(1))) void*)g,
        (__attribute__((address_space(3))) void*)l, 16, 0, 0);
}

// ---------------------------------------------------------------------------
// Build Lt[j][i] = L[i][j] in bf16 + partial sums of strict-lower Woff^2.
// ---------------------------------------------------------------------------
__global__ __launch_bounds__(256) void build_Lt(const float* __restrict__ Woff,
                                                const float* __restrict__ Wld,
                                                bf16_t* __restrict__ Lt,
                                                float* __restrict__ misc_arr) {
    __shared__ float tile[64][65];
    __shared__ float red[4];
    const int jt = blockIdx.x * 64;
    const int it = blockIdx.y * 64;
    const int tid = threadIdx.x;
    float ss = 0.f;

    if (it + 63 >= jt) {
        for (int e = tid; e < 4096; e += 256) {
            int r = e >> 6, c = e & 63;
            tile[r][c] = Woff[(size_t)(it + r) * K_DIM + (jt + c)];
        }
    }
    __syncthreads();

    for (int e = tid; e < 4096; e += 256) {
        int jr = e >> 6, ic = e & 63;
        int i = it + ic, j = jt + jr;
        float v = 0.f;
        if (i > j) {
            v = tile[ic][jr];
            ss += v * v;
        } else if (i == j) {
            v = expf(Wld[i]);
        }
        Lt[(size_t)j * K_DIM + i] = (bf16_t)v;
    }

    #pragma unroll
    for (int off = 32; off; off >>= 1) ss += __shfl_down(ss, off);
    if ((tid & 63) == 0) red[tid >> 6] = ss;
    __syncthreads();
    if (tid == 0)
        misc_arr[blockIdx.y * 32 + blockIdx.x] = red[0] + red[1] + red[2] + red[3];
}

// ---------------------------------------------------------------------------
// Cast x -> bf16 and fuse pred_mean GEMV u[b] = dot(x[b], W_mean).
// ---------------------------------------------------------------------------
__global__ __launch_bounds__(256) void prep_x(const float* __restrict__ X,
                                              const float* __restrict__ Wm,
                                              bf16_t* __restrict__ Xb,
                                              float* __restrict__ U) {
    const int b = blockIdx.x;
    const int tid = threadIdx.x;
    const float* xr = X + (size_t)b * K_DIM;
    bf16_t* xo = Xb + (size_t)b * K_DIM;
    __shared__ float red[4];
    float dot = 0.f;
    #pragma unroll
    for (int h = 0; h < 2; ++h) {
        int base = h * 1024 + tid * 4;
        float4 v = *(const float4*)(xr + base);
        float4 w = *(const float4*)(Wm + base);
        dot += v.x * w.x + v.y * w.y + v.z * w.z + v.w * w.w;
        bf16x4 p = {(bf16_t)v.x, (bf16_t)v.y, (bf16_t)v.z, (bf16_t)v.w};
        *(bf16x4*)(xo + base) = p;
    }
    #pragma unroll
    for (int off = 32; off; off >>= 1) dot += __shfl_down(dot, off);
    if ((tid & 63) == 0) red[tid >> 6] = dot;
    __syncthreads();
    if (tid == 0) U[b] = red[0] + red[1] + red[2] + red[3];
}

// ---------------------------------------------------------------------------
// quad_gemm 256x256, BK=64, 8 waves (2M x 4N), 4-phase-per-K-tile schedule
// (T3+T4+T5) with R5's proven conflict-free LDS geometry.
// LDS: As/Bs [2 buf][256 rows][64 k] bf16, 128-B rows, read XOR (row&7)<<4
// (measured 0 conflicts in R5/R7), source pre-swizzled involutively.
// Staged unit = row-half [128][64] = 16 KB = 2 gload16/wave, linear dest.
// Per tile t (reading buf[t&1]), phases:
//   ph0: ds A.mh0.ks0 + B.ks0 | stage A.h1(t+1)->buf[t+1]  | bar | MFMA16 | bar
//   ph1: ds A.mh1.ks0         | stage B.h0(t+1)->buf[t+1]  | bar | MFMA16 | bar
//   ph2: ds A.mh0.ks1 + B.ks1 | stage B.h1(t+1)->buf[t+1]  | bar | MFMA16 | bar
//   ph3: ds A.mh1.ks1         | stage A.h0(t+2)->buf[t]    | bar | MFMA16
//   end: vmcnt(2) (t+1 fully landed, t+2's A.h0 stays in flight) | bar
// Region deadness: A.h0/B.h0/B.h1 last read ph2; A.h1 last read ph3 -> every
// staged unit is >=1 barrier past its region's last reader.
// Prologue: 4 units of t0 + A.h0(t1) -> vmcnt(2) retires exactly t0.
// ---------------------------------------------------------------------------
__device__ __forceinline__ bf16x8 ldsfrag(const bf16_t* base, int row, int ks, int g) {
    int byteoff = ((row * BK + ks * 32 + g * 8) * 2) ^ ((row & 7) << 4);
    return *(const bf16x8*)((const char*)base + byteoff);
}

#define BAR() asm volatile("s_barrier" ::: "memory")
#define WAITL() { asm volatile("s_waitcnt lgkmcnt(0)" ::: "memory"); \
                  __builtin_amdgcn_sched_barrier(0); }

__global__ __launch_bounds__(512, 2) void quad_gemm(const bf16_t* __restrict__ Xb,
                                                    const bf16_t* __restrict__ Lt,
                                                    float* __restrict__ qpart) {
    __shared__ bf16_t As[2][BM * BK];   // 2 x 32 KB
    __shared__ bf16_t Bs[2][BN * BK];   // 2 x 32 KB  (128 KB total)

    const int mb = blockIdx.x;
    const int jp = blockIdx.y;              // 0..3
    const int tid = threadIdx.x;
    const int lane = tid & 63;
    const int wid = tid >> 6;               // 0..7
    const int wr = wid >> 2, wc = wid & 3;  // 2M x 4N wave grid
    const int g = lane >> 4, r16 = lane & 15;
    const int brow = mb * BM;

    // staging lane geometry: per gload16 a wave covers 8 rows x 8 chunks.
    const int srow = lane >> 3;             // 0..7 == (lds row & 7)
    const int scol = (lane & 7) ^ srow;     // pre-swizzled source chunk

    auto gemm_one = [&](int nb) {
        const int bcol = nb * BN;
        const int NT = (K_DIM - bcol) >> 6;   // in [4,32]

        // per-thread staging bases: row = (brow|bcol) + wid*16 + srow
        const bf16_t* XA = Xb + (size_t)(brow + wid * 16 + srow) * K_DIM + bcol + scol * 8;
        const bf16_t* LB = Lt + (size_t)(bcol + wid * 16 + srow) * K_DIM + bcol + scol * 8;

        auto stgA = [&](int t, int half, int buf) {
            const bf16_t* s = XA + (size_t)(half * 128) * K_DIM + t * 64;
            char* d = (char*)As[buf] + half * 16384 + wid * 2048;
            gload16(s, d);
            gload16(s + (size_t)8 * K_DIM, d + 1024);
        };
        auto stgB = [&](int t, int half, int buf) {
            const bf16_t* s = LB + (size_t)(half * 128) * K_DIM + t * 64;
            char* d = (char*)Bs[buf] + half * 16384 + wid * 2048;
            gload16(s, d);
            gload16(s + (size_t)8 * K_DIM, d + 1024);
        };

        f32x4 acc[8][4];
        const f32x4 zero = {0.f, 0.f, 0.f, 0.f};
        #pragma unroll
        for (int m = 0; m < 8; ++m)
            #pragma unroll
            for (int n = 0; n < 4; ++n) acc[m][n] = zero;

        // prologue: tile0 (4 units) then A.h0(t1); counted wait retires t0.
        stgA(0, 0, 0); stgA(0, 1, 0); stgB(0, 0, 0); stgB(0, 1, 0);
        stgA(1, 0, 1);
        asm volatile("s_waitcnt vmcnt(2)" ::: "memory");
        BAR();

        for (int t = 0; t < NT; ++t) {
            const bf16_t* Ab = As[t & 1];
            const bf16_t* Bb = Bs[t & 1];
            const int nbuf = (t + 1) & 1;
            const bool s1 = (t + 1 < NT), s2 = (t + 2 < NT);
            bf16x8 a[4], b[4];

            // ---- ph0: A.mh0.ks0 + B.ks0 | stage A.h1(t+1)
            #pragma unroll
            for (int n = 0; n < 4; ++n) b[n] = ldsfrag(Bb, wc * 64 + n * 16 + r16, 0, g);
            #pragma unroll
            for (int m = 0; m < 4; ++m) a[m] = ldsfrag(Ab, wr * 128 + m * 16 + r16, 0, g);
            if (s1) stgA(t + 1, 1, nbuf);
            BAR();
            WAITL();
            __builtin_amdgcn_s_setprio(1);
            #pragma unroll
            for (int m = 0; m < 4; ++m)
                #pragma unroll
                for (int n = 0; n < 4; ++n)
                    acc[m][n] = __builtin_amdgcn_mfma_f32_16x16x32_bf16(a[m], b[n], acc[m][n], 0, 0, 0);
            __builtin_amdgcn_s_setprio(0);
            BAR();

            // ---- ph1: A.mh1.ks0 (b cached) | stage B.h0(t+1)
            #pragma unroll
            for (int m = 0; m < 4; ++m) a[m] = ldsfrag(Ab, wr * 128 + 64 + m * 16 + r16, 0, g);
            if (s1) stgB(t + 1, 0, nbuf);
            BAR();
            WAITL();
            __builtin_amdgcn_s_setprio(1);
            #pragma unroll
            for (int m = 0; m < 4; ++m)
                #pragma unroll
                for (int n = 0; n < 4; ++n)
                    acc[4 + m][n] = __builtin_amdgcn_mfma_f32_16x16x32_bf16(a[m], b[n], acc[4 + m][n], 0, 0, 0);
            __builtin_amdgcn_s_setprio(0);
            BAR();

            // ---- ph2: A.mh0.ks1 + B.ks1 | stage B.h1(t+1)
            #pragma unroll
            for (int n = 0; n < 4; ++n) b[n] = ldsfrag(Bb, wc * 64 + n * 16 + r16, 1, g);
            #pragma unroll
            for (int m = 0; m < 4; ++m) a[m] = ldsfrag(Ab, wr * 128 + m * 16 + r16, 1, g);
            if (s1) stgB(t + 1, 1, nbuf);
            BAR();
            WAITL();
            __builtin_amdgcn_s_setprio(1);
            #pragma unroll
            for (int m = 0; m < 4; ++m)
                #pragma unroll
                for (int n = 0; n < 4; ++n)
                    acc[m][n] = __builtin_amdgcn_mfma_f32_16x16x32_bf16(a[m], b[n], acc[m][n], 0, 0, 0);
            __builtin_amdgcn_s_setprio(0);
            BAR();

            // ---- ph3: A.mh1.ks1 | stage A.h0(t+2) into current buf (dead)
            #pragma unroll
            for (int m = 0; m < 4; ++m) a[m] = ldsfrag(Ab, wr * 128 + 64 + m * 16 + r16, 1, g);
            if (s2) stgA(t + 2, 0, t & 1);
            BAR();
            WAITL();
            __builtin_amdgcn_s_setprio(1);
            #pragma unroll
            for (int m = 0; m < 4; ++m)
                #pragma unroll
                for (int n = 0; n < 4; ++n)
                    acc[4 + m][n] = __builtin_amdgcn_mfma_f32_16x16x32_bf16(a[m], b[n], acc[4 + m][n], 0, 0, 0);
            __builtin_amdgcn_s_setprio(0);

            // ---- tile end: counted wait (never drain until tail)
            if (s2)
                asm volatile("s_waitcnt vmcnt(2)" ::: "memory");
            else if (s1)
                asm volatile("s_waitcnt vmcnt(0)" ::: "memory");
            BAR();
        }

        // epilogue: per-row sum of squares over this block's 256 cols.
        // C/D: col = wc*64 + n*16 + r16, row = wr*128 + m*16 + g*4 + r
        float* qbuf = (float*)&As[0][0];  // 4 KB scratch (staging drained)
        __syncthreads();
        #pragma unroll
        for (int m = 0; m < 8; ++m) {
            #pragma unroll
            for (int r = 0; r < 4; ++r) {
                float s = 0.f;
                #pragma unroll
                for (int n = 0; n < 4; ++n) {
                    float t = acc[m][n][r];
                    s += t * t;
                }
                #pragma unroll
                for (int off = 1; off < 16; off <<= 1) s += __shfl_xor(s, off);
                if (r16 == 0) qbuf[wc * 256 + wr * 128 + m * 16 + g * 4 + r] = s;
            }
        }
        __syncthreads();
        if (tid < BM)
            qpart[(size_t)(brow + tid) * NB_N + nb] =
                qbuf[tid] + qbuf[256 + tid] + qbuf[512 + tid] + qbuf[768 + tid];
        __syncthreads();  // qbuf reads done before next gemm restages As[0]
    };

    gemm_one(jp);        // heavy: NT = 32 - 4*jp  (20..32)
    gemm_one(7 - jp);    // light: NT = 4 + 4*jp   (4..16); sum = 36 always
}
#undef BAR
#undef WAITL

// ---------------------------------------------------------------------------
// row_part: 32-block partial reduction of the per-row weighted ELBO terms.
// ---------------------------------------------------------------------------
__global__ __launch_bounds__(256) void row_part(const float* __restrict__ Y,
                                                const float* __restrict__ Cnt,
                                                const float* __restrict__ nld_p,
                                                const float* __restrict__ U,
                                                const float* __restrict__ qpart,
                                                double* __restrict__ dpart) {
    const int tid = threadIdx.x;
    const float nld = nld_p[0];
    const float inv_sig = expf(-nld);
    const float nprec = inv_sig * inv_sig;
    double s1 = 0.0, s2 = 0.0;
    const int base = blockIdx.x * 512;
    #pragma unroll
    for (int j = 0; j < 2; ++j) {
        int b = base + j * 256 + tid;
        float c = Cnt[b];
        const float4* qp = (const float4*)(qpart + (size_t)b * NB_N);
        float4 q0 = qp[0], q1 = qp[1];
        float q = q0.x + q0.y + q0.z + q0.w + q1.x + q1.y + q1.z + q1.w;
        float d = (Y[b] - U[b]) * inv_sig;
        float pl = -0.5f * d * d - nld - 0.5f * LOG2PI_F;
        float tt = 0.5f * q * c * c * nprec;
        s1 += (double)c;
        s2 += (double)((pl - tt) * c);
    }
    __shared__ double red[2][4];
    #pragma unroll
    for (int off = 32; off; off >>= 1) {
        s1 += __shfl_down(s1, off);
        s2 += __shfl_down(s2, off);
    }
    if ((tid & 63) == 0) { red[0][tid >> 6] = s1; red[1][tid >> 6] = s2; }
    __syncthreads();
    if (tid == 0) {
        dpart[blockIdx.x * 2 + 0] = red[0][0] + red[0][1] + red[0][2] + red[0][3];
        dpart[blockIdx.x * 2 + 1] = red[1][0] + red[1][1] + red[1][2] + red[1][3];
    }
}

// ---------------------------------------------------------------------------
// finalize2: combine partials + KL/wishart scalar terms. One block.
// ---------------------------------------------------------------------------
__global__ __launch_bounds__(256) void finalize2(const float* __restrict__ nld_p,
                                                 const float* __restrict__ Wm,
                                                 const float* __restrict__ Wld,
                                                 const double* __restrict__ dpart,
                                                 const float* __restrict__ misc_arr,
                                                 float* __restrict__ out) {
    const int tid = threadIdx.x;
    const float nld = nld_p[0];
    const float inv_sig = expf(-nld);
    const float nprec = inv_sig * inv_sig;

    double s1 = 0.0, s2 = 0.0;
    if (tid < 32) { s1 = dpart[tid * 2]; s2 = dpart[tid * 2 + 1]; }

    double wm2 = 0.0, tcd = 0.0, wls = 0.0, offs = 0.0;
    for (int i = tid; i < K_DIM; i += 256) {
        float w = Wm[i];
        wm2 += (double)w * (double)w;
        float ld = Wld[i];
        tcd += exp(2.0 * (double)ld);
        wls += (double)ld;
    }
    for (int i = tid; i < 1024; i += 256) offs += (double)misc_arr[i];

    __shared__ double red[6][4];
    double vals[6] = {s1, s2, wm2, tcd, wls, offs};
    #pragma unroll
    for (int s = 0; s < 6; ++s) {
        double v = vals[s];
        #pragma unroll
        for (int off = 32; off; off >>= 1) v += __shfl_down(v, off);
        if ((tid & 63) == 0) red[s][tid >> 6] = v;
    }
    __syncthreads();
    if (tid == 0) {
        double S1 = red[0][0] + red[0][1] + red[0][2] + red[0][3];
        double S2 = red[1][0] + red[1][1] + red[1][2] + red[1][3];
        double MSE = red[2][0] + red[2][1] + red[2][2] + red[2][3];
        double TCD = red[3][0] + red[3][1] + red[3][2] + red[3][3];
        double WLS = red[4][0] + red[4][1] + red[4][2] + red[4][3];
        double OFFS = red[5][0] + red[5][1] + red[5][2] + red[5][3];

        double trace_cov = OFFS + TCD;                   // sum(L*L)
        double kl = 0.5 * (MSE + trace_cov - 2.0 * WLS); // prior_scale=1
        double wish = 1.5 * (-2.0 * (double)nld) - 0.005 * (double)nprec;
        double elbo = S2 / S1 + 1e-4 * (wish - kl);
        out[0] = (float)(-elbo);
    }
}

// ---------------------------------------------------------------------------
extern "C" void kernel_launch(void* const* d_in, const int* in_sizes, int n_in,
                              void* d_out, int out_size, void* d_ws, size_t ws_size,
                              hipStream_t stream) {
    const float* x    = (const float*)d_in[0];
    const float* y    = (const float*)d_in[1];
    const float* cnt  = (const float*)d_in[2];
    // d_in[3] = noise_mean (unused by the reference math)
    const float* nld  = (const float*)d_in[4];
    const float* Wm   = (const float*)d_in[5];
    const float* Wld  = (const float*)d_in[6];
    const float* Woff = (const float*)d_in[7];

    char* ws = (char*)d_ws;
    bf16_t* Xb     = (bf16_t*)(ws);                 // [0, 67108864)
    bf16_t* Lt     = (bf16_t*)(ws + 67108864);      // [67108864, 75497472)
    float*  U      = (float*)(ws + 75497472);       // 16384*4
    float*  qpart  = (float*)(ws + 75563008);       // 16384*8*4 = 512 KB
    float*  misc   = (float*)(ws + 76611584);       // 1024*4
    // dpart (512 B) aliases Lt's base: Lt is consumed only by quad_gemm,
    // which completes before row_part writes here; build_Lt rewrites Lt
    // at the start of every launch, so replays stay deterministic.
    double* dpart  = (double*)(ws + 67108864);

    build_Lt<<<dim3(32, 32), 256, 0, stream>>>(Woff, Wld, Lt, misc);
    prep_x<<<dim3(M_DIM), 256, 0, stream>>>(x, Wm, Xb, U);
    quad_gemm<<<dim3(NB_M, 4), 512, 0, stream>>>(Xb, Lt, qpart);
    row_part<<<dim3(32), 256, 0, stream>>>(y, cnt, nld, U, qpart, dpart);
    finalize2<<<1, 256, 0, stream>>>(nld, Wm, Wld, dpart, misc, (float*)d_out);
}